// Round 2
// baseline (136.534 us; speedup 1.0000x reference)
//
#include <hip/hip_runtime.h>
#include <math.h>

#define DIMC 768
#define BATCH 16
#define HWSZ 1024
#define NT 32

// out layout: result [16*32*768] | p [16*32*768] | mask [16*32*1024]
#define OUT_P_OFF    393216
#define OUT_MASK_OFF 786432

// ws layout: wt [768*32] f32 (98304 B) | s [16*32*1024] f32 (2 MB)
#define WS_S_OFF_FLOATS 24576

// ---------------- K0: init s = pw_bias, and transpose pww -> wt[c][t] -------
__global__ __launch_bounds__(256) void k0_init(
    const float* __restrict__ pwb, const float* __restrict__ pww,
    float* __restrict__ wt, float* __restrict__ s)
{
    int blk = blockIdx.x;
    int tid = threadIdx.x;
    if (blk < 2048) {
        int i = blk * 256 + tid;          // < 16*32*1024
        int t = (i >> 10) & 31;
        s[i] = pwb[t];
    } else {
        int i = (blk - 2048) * 256 + tid; // < 768*32
        int c = i >> 5, t = i & 31;
        wt[i] = pww[t * DIMC + c];        // wt[c*32+t]
    }
}

// ---------------- KF: fused BN + dw3x3 + hardswish + pointwise --------------
// grid (pos-chunk=4, c-chunk=8, b=16) = 512 blocks, 256 threads.
// Block owns: batch b, 256 positions (8 rows), 96 channels.
// Lane owns one position; 32 token accumulators in VGPRs.
__global__ __launch_bounds__(256) void kf_fused(
    const float* __restrict__ x,
    const float* __restrict__ bnw, const float* __restrict__ bnb,
    const float* __restrict__ bnm, const float* __restrict__ bnv,
    const float* __restrict__ dww, const float* __restrict__ dwb,
    const float* __restrict__ wt,
    float* __restrict__ s)
{
    const int b   = blockIdx.z;
    const int cc0 = blockIdx.y * 96;          // channel chunk start
    const int r0  = blockIdx.x * 8;           // first output row of this block
    const int tid = threadIdx.x;
    const int rl  = tid >> 5;                 // local row 0..7
    const int col = tid & 31;
    const int pos = r0 * 32 + tid;            // global position 0..1023

    // staged tile: rows r0-1 .. r0+8 (10), cols -1..32 (34), zero-padded, BN'd
    __shared__ float st[2][10][34];

    float acc[NT];
#pragma unroll
    for (int t = 0; t < NT; ++t) acc[t] = 0.0f;

    const float* xb = x + ((size_t)b * DIMC) * HWSZ;

    // stage channel c into buffer buf
    auto stage = [&](int buf, int c) {
        float scale = bnw[c] * rsqrtf(bnv[c] + 1e-5f);
        float shift = bnb[c] - bnm[c] * scale;
        const float* xp = xb + (size_t)c * HWSZ;
        for (int i = tid; i < 340; i += 256) {
            int sr = i / 34, sc = i % 34;
            int rr = r0 - 1 + sr;
            int ccol = sc - 1;
            float v = 0.0f;
            if (rr >= 0 && rr < 32 && ccol >= 0 && ccol < 32)
                v = xp[rr * 32 + ccol] * scale + shift;
            st[buf][sr][sc] = v;
        }
    };

    stage(0, cc0);
    __syncthreads();

    for (int k = 0; k < 96; ++k) {
        int cur = k & 1;
        int c = cc0 + k;
        if (k + 1 < 96) stage(cur ^ 1, c + k >= c ? c + 1 : c + 1); // c+1
        // depthwise 3x3 (zero-padded) from staged tile
        const float* wd = dww + c * 9;        // uniform -> s_load
        float r = dwb[c];
#pragma unroll
        for (int dr = 0; dr < 3; ++dr)
#pragma unroll
            for (int dc = 0; dc < 3; ++dc)
                r += wd[dr * 3 + dc] * st[cur][rl + dr][col + dc];
        // hardswish
        float cl = fminf(fmaxf(r + 3.0f, 0.0f), 6.0f);
        float hs = r * cl * (1.0f / 6.0f);
        // pointwise: 32 token FMAs, weights uniform (SGPR)
        const float* wv = wt + (size_t)c * NT;
#pragma unroll
        for (int t = 0; t < NT; ++t)
            acc[t] += hs * wv[t];
        __syncthreads();
    }

    float* sp = s + (size_t)b * NT * HWSZ + pos;
#pragma unroll
    for (int t = 0; t < NT; ++t)
        atomicAdd(sp + (size_t)t * HWSZ, acc[t]);
}

// ---------------- K3: argmax mask + gather-sum ----------------
__global__ __launch_bounds__(256) void k3_mask_gather(
    const float* __restrict__ s,
    const float* __restrict__ x, const float* __restrict__ posin,
    const float* __restrict__ bnw, const float* __restrict__ bnb,
    const float* __restrict__ bnm, const float* __restrict__ bnv,
    float* __restrict__ out)
{
    int bt = blockIdx.x;           // b*32 + t
    int b  = bt >> 5;
    int tid = threadIdx.x;

    const float* sp = s + (size_t)bt * HWSZ;
    float v[4];
    float m = -INFINITY;
#pragma unroll
    for (int i = 0; i < 4; ++i) {
        v[i] = sp[tid + 256 * i];
        m = fmaxf(m, v[i]);
    }
#pragma unroll
    for (int off = 32; off; off >>= 1)
        m = fmaxf(m, __shfl_xor(m, off));
    __shared__ float wm[4];
    if ((tid & 63) == 0) wm[tid >> 6] = m;
    __syncthreads();
    m = fmaxf(fmaxf(wm[0], wm[1]), fmaxf(wm[2], wm[3]));

    __shared__ int nmatch;
    __shared__ int matchpos[16];
    if (tid == 0) nmatch = 0;
    __syncthreads();

    float* maskp = out + OUT_MASK_OFF + (size_t)bt * HWSZ;
#pragma unroll
    for (int i = 0; i < 4; ++i) {
        int pos = tid + 256 * i;
        int hit = (v[i] == m);
        maskp[pos] = hit ? 1.0f : 0.0f;
        if (hit) {
            int k = atomicAdd(&nmatch, 1);
            if (k < 16) matchpos[k] = pos;
        }
    }
    __syncthreads();
    int nm = nmatch < 16 ? nmatch : 16;

    const float* xb = x + (size_t)b * DIMC * HWSZ;
    const float* pb = posin + (size_t)b * DIMC * HWSZ;
    for (int c = tid; c < DIMC; c += 256) {
        float scale = bnw[c] * rsqrtf(bnv[c] + 1e-5f);
        float shift = bnb[c] - bnm[c] * scale;
        float rf = 0.0f, rp = 0.0f;
        for (int k = 0; k < nm; ++k) {
            int pos = matchpos[k];
            rf += xb[(size_t)c * HWSZ + pos] * scale + shift;
            rp += pb[(size_t)c * HWSZ + pos];
        }
        out[(size_t)bt * DIMC + c] = rf;
        out[OUT_P_OFF + (size_t)bt * DIMC + c] = rp;
    }
}

extern "C" void kernel_launch(void* const* d_in, const int* in_sizes, int n_in,
                              void* d_out, int out_size, void* d_ws, size_t ws_size,
                              hipStream_t stream)
{
    const float* x    = (const float*)d_in[0];
    const float* pos  = (const float*)d_in[1];
    const float* bnw  = (const float*)d_in[2];
    const float* bnb  = (const float*)d_in[3];
    const float* bnm  = (const float*)d_in[4];
    const float* bnv  = (const float*)d_in[5];
    const float* dww  = (const float*)d_in[6];
    const float* dwb  = (const float*)d_in[7];
    const float* pww  = (const float*)d_in[8];
    const float* pwb  = (const float*)d_in[9];
    float* out = (float*)d_out;

    float* wt = (float*)d_ws;
    float* s  = (float*)d_ws + WS_S_OFF_FLOATS;

    k0_init<<<2048 + 96, 256, 0, stream>>>(pwb, pww, wt, s);
    kf_fused<<<dim3(4, 8, BATCH), 256, 0, stream>>>(x, bnw, bnb, bnm, bnv,
                                                    dww, dwb, wt, s);
    k3_mask_gather<<<BATCH * NT, 256, 0, stream>>>(s, x, pos, bnw, bnb, bnm, bnv, out);
}

// Round 3
// 77.349 us; speedup vs baseline: 1.7652x; 1.7652x over previous
//
#include <hip/hip_runtime.h>
#include <math.h>

#define DIMC 768
#define BATCH 16
#define HWSZ 1024
#define NT 32

// out layout: result [16*32*768] | p [16*32*768] | mask [16*32*1024]
#define OUT_P_OFF    393216
#define OUT_MASK_OFF 786432

// ws layout (floats): h [16*768*1024] | s [16*32*1024] | wt [768*32]
#define WS_S_OFF   12582912
#define WS_WT_OFF  13107200

// ---------------- K0: init s = pw_bias, transpose pww -> wt[c][t] ----------
__global__ __launch_bounds__(256) void k0_init(
    const float* __restrict__ pwb, const float* __restrict__ pww,
    float* __restrict__ wt, float* __restrict__ s)
{
    int blk = blockIdx.x;
    int tid = threadIdx.x;
    if (blk < 2048) {
        int i = blk * 256 + tid;          // < 16*32*1024
        int t = (i >> 10) & 31;
        s[i] = pwb[t];
    } else {
        int i = (blk - 2048) * 256 + tid; // < 768*32
        int c = i >> 5, t = i & 31;
        wt[i] = pww[t * DIMC + c];        // wt[c*32+t]
    }
}

// ---------------- K1': BN + dw3x3 + hardswish, strip-vectorized ------------
// one block per (b,c) plane; lane owns a 1x4 strip (row=tid>>3, col0=(tid&7)*4)
__global__ __launch_bounds__(256) void k1_bn_dw_hsw(
    const float* __restrict__ x,
    const float* __restrict__ bnw, const float* __restrict__ bnb,
    const float* __restrict__ bnm, const float* __restrict__ bnv,
    const float* __restrict__ dww, const float* __restrict__ dwb,
    float* __restrict__ h)
{
    const int bc  = blockIdx.x;
    const int c   = bc % DIMC;
    const int tid = threadIdx.x;
    __shared__ float tile[32][32];

    float scale = bnw[c] * rsqrtf(bnv[c] + 1e-5f);
    float shift = bnb[c] - bnm[c] * scale;

    const float4* xp4 = (const float4*)(x + (size_t)bc * HWSZ);
    float4 v = xp4[tid];
    v.x = v.x * scale + shift;
    v.y = v.y * scale + shift;
    v.z = v.z * scale + shift;
    v.w = v.w * scale + shift;
    ((float4*)tile)[tid] = v;
    __syncthreads();

    const float* wd = dww + c * 9;        // block-uniform -> SGPR
    const float w0 = wd[0], w1 = wd[1], w2 = wd[2],
                w3 = wd[3], w4 = wd[4], w5 = wd[5],
                w6 = wd[6], w7 = wd[7], w8 = wd[8];
    const float bias = dwb[c];

    const int row  = tid >> 3;
    const int col0 = (tid & 7) << 2;

    float vt[6], vm[6], vb[6];
    // middle row (always valid)
    {
        const float4 m = *(const float4*)&tile[row][col0];
        vm[0] = (col0 > 0)  ? tile[row][col0 - 1] : 0.0f;
        vm[1] = m.x; vm[2] = m.y; vm[3] = m.z; vm[4] = m.w;
        vm[5] = (col0 < 28) ? tile[row][col0 + 4] : 0.0f;
    }
    if (row > 0) {
        const float4 m = *(const float4*)&tile[row - 1][col0];
        vt[0] = (col0 > 0)  ? tile[row - 1][col0 - 1] : 0.0f;
        vt[1] = m.x; vt[2] = m.y; vt[3] = m.z; vt[4] = m.w;
        vt[5] = (col0 < 28) ? tile[row - 1][col0 + 4] : 0.0f;
    } else {
#pragma unroll
        for (int j = 0; j < 6; ++j) vt[j] = 0.0f;
    }
    if (row < 31) {
        const float4 m = *(const float4*)&tile[row + 1][col0];
        vb[0] = (col0 > 0)  ? tile[row + 1][col0 - 1] : 0.0f;
        vb[1] = m.x; vb[2] = m.y; vb[3] = m.z; vb[4] = m.w;
        vb[5] = (col0 < 28) ? tile[row + 1][col0 + 4] : 0.0f;
    } else {
#pragma unroll
        for (int j = 0; j < 6; ++j) vb[j] = 0.0f;
    }

    float4 o;
    float* op = &o.x;
#pragma unroll
    for (int j = 0; j < 4; ++j) {
        float r = bias
                + w0 * vt[j] + w1 * vt[j + 1] + w2 * vt[j + 2]
                + w3 * vm[j] + w4 * vm[j + 1] + w5 * vm[j + 2]
                + w6 * vb[j] + w7 * vb[j + 1] + w8 * vb[j + 2];
        float cl = fminf(fmaxf(r + 3.0f, 0.0f), 6.0f);
        op[j] = r * cl * (1.0f / 6.0f);
    }
    ((float4*)(h + (size_t)bc * HWSZ))[tid] = o;
}

// ---------------- K2': pointwise 768->32, 48-ch chunks, unroll-8 ILP -------
// grid (poschunk=4, cchunk=16, b=16) = 1024 blocks, 256 threads
__global__ __launch_bounds__(256) void k2_pointwise(
    const float* __restrict__ h, const float* __restrict__ wt,
    float* __restrict__ s)
{
    const int b   = blockIdx.z;
    const int cc0 = blockIdx.y * 48;
    const int pos = blockIdx.x * 256 + threadIdx.x;

    const float* hp = h + ((size_t)(b * DIMC + cc0)) * HWSZ + pos;
    const float* wp = wt + (size_t)cc0 * NT;

    float acc[NT];
#pragma unroll
    for (int t = 0; t < NT; ++t) acc[t] = 0.0f;

    for (int g = 0; g < 48; g += 8) {
        float hv[8];
#pragma unroll
        for (int u = 0; u < 8; ++u)
            hv[u] = hp[(size_t)(g + u) * HWSZ];
#pragma unroll
        for (int u = 0; u < 8; ++u) {
            const float* wv = wp + (g + u) * NT;   // uniform -> s_load
#pragma unroll
            for (int t = 0; t < NT; ++t)
                acc[t] += hv[u] * wv[t];
        }
    }

    float* sp = s + (size_t)b * NT * HWSZ + pos;
#pragma unroll
    for (int t = 0; t < NT; ++t)
        atomicAdd(sp + (size_t)t * HWSZ, acc[t]);
}

// ---------------- K3: argmax mask + gather-sum ----------------
__global__ __launch_bounds__(256) void k3_mask_gather(
    const float* __restrict__ s,
    const float* __restrict__ x, const float* __restrict__ posin,
    const float* __restrict__ bnw, const float* __restrict__ bnb,
    const float* __restrict__ bnm, const float* __restrict__ bnv,
    float* __restrict__ out)
{
    int bt = blockIdx.x;           // b*32 + t
    int b  = bt >> 5;
    int tid = threadIdx.x;

    const float* sp = s + (size_t)bt * HWSZ;
    float v[4];
    float m = -INFINITY;
#pragma unroll
    for (int i = 0; i < 4; ++i) {
        v[i] = sp[tid + 256 * i];
        m = fmaxf(m, v[i]);
    }
#pragma unroll
    for (int off = 32; off; off >>= 1)
        m = fmaxf(m, __shfl_xor(m, off));
    __shared__ float wm[4];
    if ((tid & 63) == 0) wm[tid >> 6] = m;
    __syncthreads();
    m = fmaxf(fmaxf(wm[0], wm[1]), fmaxf(wm[2], wm[3]));

    __shared__ int nmatch;
    __shared__ int matchpos[16];
    if (tid == 0) nmatch = 0;
    __syncthreads();

    float* maskp = out + OUT_MASK_OFF + (size_t)bt * HWSZ;
#pragma unroll
    for (int i = 0; i < 4; ++i) {
        int pos = tid + 256 * i;
        int hit = (v[i] == m);
        maskp[pos] = hit ? 1.0f : 0.0f;
        if (hit) {
            int k = atomicAdd(&nmatch, 1);
            if (k < 16) matchpos[k] = pos;
        }
    }
    __syncthreads();
    int nm = nmatch < 16 ? nmatch : 16;

    const float* xb = x + (size_t)b * DIMC * HWSZ;
    const float* pb = posin + (size_t)b * DIMC * HWSZ;
    for (int c = tid; c < DIMC; c += 256) {
        float scale = bnw[c] * rsqrtf(bnv[c] + 1e-5f);
        float shift = bnb[c] - bnm[c] * scale;
        float rf = 0.0f, rp = 0.0f;
        for (int k = 0; k < nm; ++k) {
            int pos = matchpos[k];
            rf += xb[(size_t)c * HWSZ + pos] * scale + shift;
            rp += pb[(size_t)c * HWSZ + pos];
        }
        out[(size_t)bt * DIMC + c] = rf;
        out[OUT_P_OFF + (size_t)bt * DIMC + c] = rp;
    }
}

extern "C" void kernel_launch(void* const* d_in, const int* in_sizes, int n_in,
                              void* d_out, int out_size, void* d_ws, size_t ws_size,
                              hipStream_t stream)
{
    const float* x    = (const float*)d_in[0];
    const float* pos  = (const float*)d_in[1];
    const float* bnw  = (const float*)d_in[2];
    const float* bnb  = (const float*)d_in[3];
    const float* bnm  = (const float*)d_in[4];
    const float* bnv  = (const float*)d_in[5];
    const float* dww  = (const float*)d_in[6];
    const float* dwb  = (const float*)d_in[7];
    const float* pww  = (const float*)d_in[8];
    const float* pwb  = (const float*)d_in[9];
    float* out = (float*)d_out;

    float* h  = (float*)d_ws;
    float* s  = (float*)d_ws + WS_S_OFF;
    float* wt = (float*)d_ws + WS_WT_OFF;

    k0_init<<<2048 + 96, 256, 0, stream>>>(pwb, pww, wt, s);
    k1_bn_dw_hsw<<<BATCH * DIMC, 256, 0, stream>>>(x, bnw, bnb, bnm, bnv,
                                                   dww, dwb, h);
    k2_pointwise<<<dim3(4, 16, BATCH), 256, 0, stream>>>(h, wt, s);
    k3_mask_gather<<<BATCH * NT, 256, 0, stream>>>(s, x, pos, bnw, bnb, bnm, bnv, out);
}

// Round 4
// 66.829 us; speedup vs baseline: 2.0430x; 1.1574x over previous
//
#include <hip/hip_runtime.h>
#include <math.h>

#define DIMC 768
#define BATCH 16
#define HWSZ 1024
#define NT 32
#define SCH 16          // channel splits
#define CHPB 48         // channels per block (768/16)

// out layout: result [16*32*768] | p [16*32*768] | mask [16*32*1024]
#define OUT_P_OFF    393216
#define OUT_MASK_OFF 786432

// ws layout (floats): partials [16][16][32][1024] = 8388608 | wt [768*32]
#define WS_WT_OFF 8388608

// ---------------- K0: transpose pww[t][c] -> wt[c][t] ----------------------
__global__ __launch_bounds__(256) void k0_transpose(
    const float* __restrict__ pww, float* __restrict__ wt)
{
    int i = blockIdx.x * 256 + threadIdx.x;   // < 768*32
    wt[i] = pww[(i & 31) * DIMC + (i >> 5)];
}

// ---------------- KF: fused BN + dw3x3 + hardswish + pointwise partials ----
// grid (pos-chunk=4, ch-chunk=16, b=16), 256 threads; lane owns one position.
// LDS: double-buffered 10x34 zero-padded BN'd channel tile (2.7 KB).
// 32 named accumulators -> guaranteed VGPRs (round-1/2 spill post-mortem).

#define ACC4(G) float a##G##0 = 0.f, a##G##1 = 0.f, a##G##2 = 0.f, a##G##3 = 0.f;
#define PW4(G, W) { a##G##0 = fmaf(hs, W.x, a##G##0); a##G##1 = fmaf(hs, W.y, a##G##1); \
                    a##G##2 = fmaf(hs, W.z, a##G##2); a##G##3 = fmaf(hs, W.w, a##G##3); }
#define STG4(G) { po[(size_t)(4*G+0) << 10] = a##G##0; po[(size_t)(4*G+1) << 10] = a##G##1; \
                  po[(size_t)(4*G+2) << 10] = a##G##2; po[(size_t)(4*G+3) << 10] = a##G##3; }

__global__ __launch_bounds__(256) void kf_fused(
    const float* __restrict__ x,
    const float* __restrict__ bnw, const float* __restrict__ bnb,
    const float* __restrict__ bnm, const float* __restrict__ bnv,
    const float* __restrict__ dww, const float* __restrict__ dwb,
    const float* __restrict__ wt,
    float* __restrict__ partials)
{
    const int b   = blockIdx.z;
    const int scc = blockIdx.y;
    const int cb0 = scc * CHPB;
    const int r0  = blockIdx.x * 8;           // first output row
    const int tid = threadIdx.x;
    const int rl  = tid >> 5;                 // local row 0..7
    const int col = tid & 31;

    __shared__ float st[2][340];              // [buf][10*34], zero-padded halo
    float* S0 = &st[0][0];
    for (int i = tid; i < 680; i += 256) S0[i] = 0.0f;

    // channel-independent staging geometry (flat LDS index == tid, tid+256)
    const int i1t = tid + 256;
    const int sr0 = tid / 34, sc0 = tid - sr0 * 34;
    const int sr1 = i1t / 34, sc1 = i1t - sr1 * 34;
    const int rr0 = r0 - 1 + sr0, cl0 = sc0 - 1;
    const int rr1 = r0 - 1 + sr1, cl1 = sc1 - 1;
    const bool valid0 = (rr0 >= 0 && rr0 < 32 && cl0 >= 0 && cl0 < 32);
    const bool valid1 = (i1t < 340) && (rr1 >= 0 && rr1 < 32 && cl1 >= 0 && cl1 < 32);
    const int off0 = rr0 * 32 + cl0;
    const int off1 = rr1 * 32 + cl1;

    const float* xb = x + (size_t)(b * DIMC) * HWSZ;

    // prologue: stage channel cb0 into buf 0
    {
        const int c = cb0;
        float scale = bnw[c] * rsqrtf(bnv[c] + 1e-5f);
        float shift = bnb[c] - bnm[c] * scale;
        const float* xc = xb + (size_t)c * HWSZ;
        if (valid0) st[0][tid] = xc[off0] * scale + shift;
        if (valid1) st[0][i1t] = xc[off1] * scale + shift;
    }
    __syncthreads();

    ACC4(0) ACC4(1) ACC4(2) ACC4(3) ACC4(4) ACC4(5) ACC4(6) ACC4(7)

    const int base = rl * 34 + col;

    for (int k = 0; k < CHPB; ++k) {
        const int c = cb0 + k;
        const float* S = st[k & 1];

        // T14 split-stage: issue next channel's global loads before compute
        float g0 = 0.f, g1 = 0.f, scale = 0.f, shift = 0.f;
        if (k < CHPB - 1) {
            const int cn = c + 1;
            scale = bnw[cn] * rsqrtf(bnv[cn] + 1e-5f);
            shift = bnb[cn] - bnm[cn] * scale;
            const float* xc = xb + (size_t)cn * HWSZ;
            if (valid0) g0 = xc[off0];
            if (valid1) g1 = xc[off1];
        }

        // depthwise 3x3 from staged tile (uniform weights -> s_load)
        const float* wd = dww + c * 9;
        float racc = dwb[c];
        racc = fmaf(wd[0], S[base +  0], racc);
        racc = fmaf(wd[1], S[base +  1], racc);
        racc = fmaf(wd[2], S[base +  2], racc);
        racc = fmaf(wd[3], S[base + 34], racc);
        racc = fmaf(wd[4], S[base + 35], racc);
        racc = fmaf(wd[5], S[base + 36], racc);
        racc = fmaf(wd[6], S[base + 68], racc);
        racc = fmaf(wd[7], S[base + 69], racc);
        racc = fmaf(wd[8], S[base + 70], racc);
        float clp = fminf(fmaxf(racc + 3.0f, 0.0f), 6.0f);
        float hs  = racc * clp * (1.0f / 6.0f);

        // pointwise: 32 token FMAs, uniform weights
        const float4* wv = (const float4*)(wt + c * NT);
        float4 wA = wv[0], wB = wv[1], wC = wv[2], wD = wv[3],
               wE = wv[4], wF = wv[5], wG = wv[6], wH = wv[7];
        PW4(0, wA) PW4(1, wB) PW4(2, wC) PW4(3, wD)
        PW4(4, wE) PW4(5, wF) PW4(6, wG) PW4(7, wH)

        // late staging write (loads have been in flight across the compute)
        if (k < CHPB - 1) {
            float* Sn = &st[(k & 1) ^ 1][0];
            if (valid0) Sn[tid] = fmaf(g0, scale, shift);
            if (valid1) Sn[i1t] = fmaf(g1, scale, shift);
        }
        __syncthreads();
    }

    float* po = partials + ((size_t)(scc * BATCH + b) * NT) * HWSZ
              + blockIdx.x * 256 + tid;
    STG4(0) STG4(1) STG4(2) STG4(3) STG4(4) STG4(5) STG4(6) STG4(7)
}

// ---------------- K3: sum partials -> argmax mask -> gather-sum ------------
__global__ __launch_bounds__(256) void k3_mask_gather(
    const float* __restrict__ partials,
    const float* __restrict__ x, const float* __restrict__ posin,
    const float* __restrict__ bnw, const float* __restrict__ bnb,
    const float* __restrict__ bnm, const float* __restrict__ bnv,
    float* __restrict__ out)
{
    int bt = blockIdx.x;           // b*32 + t
    int b  = bt >> 5;
    int t  = bt & 31;
    int tid = threadIdx.x;

    const float* pp = partials + ((size_t)(b * NT) + t) * HWSZ;
    float v[4];
    float m = -INFINITY;
#pragma unroll
    for (int i = 0; i < 4; ++i) {
        int pos = tid + 256 * i;
        float acc = 0.0f;
#pragma unroll
        for (int s = 0; s < SCH; ++s)
            acc += pp[(size_t)s * (BATCH * NT * HWSZ) + pos];
        v[i] = acc;
        m = fmaxf(m, acc);
    }
#pragma unroll
    for (int off = 32; off; off >>= 1)
        m = fmaxf(m, __shfl_xor(m, off));
    __shared__ float wm[4];
    if ((tid & 63) == 0) wm[tid >> 6] = m;
    __syncthreads();
    m = fmaxf(fmaxf(wm[0], wm[1]), fmaxf(wm[2], wm[3]));

    __shared__ int nmatch;
    __shared__ int matchpos[16];
    if (tid == 0) nmatch = 0;
    __syncthreads();

    float* maskp = out + OUT_MASK_OFF + (size_t)bt * HWSZ;
#pragma unroll
    for (int i = 0; i < 4; ++i) {
        int pos = tid + 256 * i;
        int hit = (v[i] == m);
        maskp[pos] = hit ? 1.0f : 0.0f;
        if (hit) {
            int k = atomicAdd(&nmatch, 1);
            if (k < 16) matchpos[k] = pos;
        }
    }
    __syncthreads();
    int nm = nmatch < 16 ? nmatch : 16;

    const float* xb = x + (size_t)b * DIMC * HWSZ;
    const float* pb = posin + (size_t)b * DIMC * HWSZ;
    for (int c = tid; c < DIMC; c += 256) {
        float scale = bnw[c] * rsqrtf(bnv[c] + 1e-5f);
        float shift = bnb[c] - bnm[c] * scale;
        float rf = 0.0f, rp = 0.0f;
        for (int k = 0; k < nm; ++k) {
            int pos = matchpos[k];
            rf += xb[(size_t)c * HWSZ + pos] * scale + shift;
            rp += pb[(size_t)c * HWSZ + pos];
        }
        out[(size_t)bt * DIMC + c] = rf;
        out[OUT_P_OFF + (size_t)bt * DIMC + c] = rp;
    }
}

extern "C" void kernel_launch(void* const* d_in, const int* in_sizes, int n_in,
                              void* d_out, int out_size, void* d_ws, size_t ws_size,
                              hipStream_t stream)
{
    const float* x    = (const float*)d_in[0];
    const float* pos  = (const float*)d_in[1];
    const float* bnw  = (const float*)d_in[2];
    const float* bnb  = (const float*)d_in[3];
    const float* bnm  = (const float*)d_in[4];
    const float* bnv  = (const float*)d_in[5];
    const float* dww  = (const float*)d_in[6];
    const float* dwb  = (const float*)d_in[7];
    const float* pww  = (const float*)d_in[8];
    // d_in[9] (pw_bias) intentionally unused: constant per (b,t) row ->
    // argmax/mask/result/p are invariant to it.
    float* out = (float*)d_out;

    float* partials = (float*)d_ws;
    float* wt       = (float*)d_ws + WS_WT_OFF;

    k0_transpose<<<96, 256, 0, stream>>>(pww, wt);
    kf_fused<<<dim3(4, SCH, BATCH), 256, 0, stream>>>(x, bnw, bnb, bnm, bnv,
                                                      dww, dwb, wt, partials);
    k3_mask_gather<<<BATCH * NT, 256, 0, stream>>>(partials, x, pos,
                                                   bnw, bnb, bnm, bnv, out);
}